// Round 9
// baseline (55.587 us; speedup 1.0000x reference)
//
#include <hip/hip_runtime.h>
#include <hip/hip_bf16.h>
#include <hip/hip_fp16.h>

// Problem constants (fixed by setup_inputs)
#define CIN      8
#define HH       100
#define WW       152
#define HWSZ     (HH * WW)          // 15200
#define OHGT     200
#define OWID     304
#define PPI      419                 // params per instance: 169 body + 169 edge + 81 fused
#define OUT_PER_INST (OHGT * OWID)   // 60800

// Per-instance param layout (row of 419 floats):
//  body:  w1[8][10]@0  w2[8][8]@80  w3[8]@144  b1[8]@152 b2[8]@160 b3@168
//  edge:  same +169
//  fused: wf1[8][8]@338 wf2[8]@402 bf1[8]@410 bf2@418

typedef float vf4 __attribute__((ext_vector_type(4)));

// EXPLICIT per-component fmaf: guarantees v_fma_f32 emission (R8 theory: the
// w*x+a form may have lowered to v_mul+v_add, doubling K1's issue count).
__device__ __forceinline__ vf4 fma4(float w, vf4 x, vf4 a) {
    vf4 r;
    r.x = fmaf(w, x.x, a.x);
    r.y = fmaf(w, x.y, a.y);
    r.z = fmaf(w, x.z, a.z);
    r.w = fmaf(w, x.w, a.w);
    return r;
}
__device__ __forceinline__ vf4 relu4(vf4 x) {
    vf4 r; r.x = fmaxf(x.x, 0.f); r.y = fmaxf(x.y, 0.f);
    r.z = fmaxf(x.z, 0.f); r.w = fmaxf(x.w, 0.f); return r;
}
__device__ __forceinline__ void store_h4(__half* dst, vf4 v) {
    union { __half2 h[2]; uint2 u; } pk;
    pk.h[0] = __floats2half2_rn(v.x, v.y);
    pk.h[1] = __floats2half2_rn(v.z, v.w);
    *(uint2*)dst = pk.u;   // single 8B store (dst 8B-aligned: px%4==0)
}

// ------------------------------------------------------------------------
// K1: per-pixel-quad dynamic MLPs -> logits[3][n_inst][100][152] (fp16, d_ws)
// FOUR adjacent pixels per thread (quads never cross rows: WW=152 % 4 == 0).
// Straight-line, no pixel loop: weight s_loads single-use -> no hoist/spill.
// ------------------------------------------------------------------------
__global__ __launch_bounds__(256) void dmh_mlp4_kernel(
    const float* __restrict__ fbody,      // [2][8][H][W]
    const float* __restrict__ fedge,      // [2][8][H][W]
    const float* __restrict__ params,     // [n_inst][419]
    const float* __restrict__ locs,       // [n_inst][2]
    const float* __restrict__ soi_tab,    // [5]
    const int*   __restrict__ im_inds,    // [n_inst]
    const int*   __restrict__ fpn_levels, // [n_inst]
    __half* __restrict__ logits,          // [3][n_inst][HWSZ]
    int n_inst)
{
    const int n  = blockIdx.y;
    const int i  = blockIdx.x * 256 + threadIdx.x;
    const int px = 4 * i;                 // quad (px..px+3), single row
    if (px >= HWSZ) return;

    const float* __restrict__ p = params + (size_t)n * PPI;
    const int   im      = im_inds[n];
    const float inv_soi = 1.0f / soi_tab[fpn_levels[n]];
    const float sx = (locs[2 * n]     - 4.0f) * inv_soi;
    const float sy = (locs[2 * n + 1] - 4.0f) * inv_soi;
    const float k8 = 8.0f * inv_soi;

    const int r = px / WW;
    const int c = px - r * WW;
    const float dx0 = sx - (float)c * k8;
    const vf4 dx = { dx0, dx0 - k8, dx0 - 2.f * k8, dx0 - 3.f * k8 };
    const float dyv = sy - (float)r * k8;
    const vf4 dy = { dyv, dyv, dyv, dyv };

    const float* __restrict__ fb = fbody + (size_t)im * CIN * HWSZ + px;
    const float* __restrict__ fe = fedge + (size_t)im * CIN * HWSZ + px;

    vf4 in[10], h1[8];

    // ---------------- body head ----------------
    in[0] = dx; in[1] = dy;
    #pragma unroll
    for (int k = 0; k < 8; ++k)
        in[k + 2] = *(const vf4*)(fb + k * HWSZ);   // 16B coalesced, aligned
    #pragma unroll
    for (int o = 0; o < 8; ++o) {
        vf4 a = p[152 + o];
        #pragma unroll
        for (int k = 0; k < 10; ++k) a = fma4(p[o * 10 + k], in[k], a);
        h1[o] = relu4(a);
    }
    vf4 h2b[8];
    #pragma unroll
    for (int o = 0; o < 8; ++o) {
        vf4 a = p[160 + o];
        #pragma unroll
        for (int k = 0; k < 8; ++k) a = fma4(p[80 + o * 8 + k], h1[k], a);
        h2b[o] = relu4(a);
    }
    vf4 lb = p[168];
    #pragma unroll
    for (int k = 0; k < 8; ++k) lb = fma4(p[144 + k], h2b[k], lb);

    // ---------------- edge head (reuses in/h1) ----------------
    #pragma unroll
    for (int k = 0; k < 8; ++k)
        in[k + 2] = *(const vf4*)(fe + k * HWSZ);
    #pragma unroll
    for (int o = 0; o < 8; ++o) {
        vf4 a = p[169 + 152 + o];
        #pragma unroll
        for (int k = 0; k < 10; ++k) a = fma4(p[169 + o * 10 + k], in[k], a);
        h1[o] = relu4(a);
    }
    vf4 h2e[8];
    #pragma unroll
    for (int o = 0; o < 8; ++o) {
        vf4 a = p[169 + 160 + o];
        #pragma unroll
        for (int k = 0; k < 8; ++k) a = fma4(p[169 + 80 + o * 8 + k], h1[k], a);
        h2e[o] = relu4(a);
    }
    vf4 le = p[169 + 168];
    #pragma unroll
    for (int k = 0; k < 8; ++k) le = fma4(p[169 + 144 + k], h2e[k], le);

    // ---------------- fused head on relu(h2b)+relu(h2e) ----------------
    vf4 hs[8];
    #pragma unroll
    for (int k = 0; k < 8; ++k) hs[k] = h2b[k] + h2e[k];
    vf4 hf[8];
    #pragma unroll
    for (int o = 0; o < 8; ++o) {
        vf4 a = p[410 + o];
        #pragma unroll
        for (int k = 0; k < 8; ++k) a = fma4(p[338 + o * 8 + k], hs[k], a);
        hf[o] = relu4(a);
    }
    vf4 lf = p[418];
    #pragma unroll
    for (int k = 0; k < 8; ++k) lf = fma4(p[402 + k], hf[k], lf);

    const size_t hstride = (size_t)n_inst * HWSZ;
    __half* lg = logits + (size_t)n * HWSZ + px;
    store_h4(lg,               lb);
    store_h4(lg + hstride,     le);
    store_h4(lg + 2 * hstride, lf);
}

// ------------------------------------------------------------------------
// K2: aligned_bilinear x2 + sigmoid + fp32 store. REGULAR stores (R8 A/B:
// NT stores suspected to have cost ~+3 us in R7's bundle — the harness fill
// kernel hits 6.4 TB/s with regular stores through L2).
// Thread <-> (h*n_inst+n, r, q). 2 rows x 4 cols of output per thread from
// 6 fp16 logit loads. Closed form: out[y][x] samples logit grid at
// (i,j)=(max(y-1,0),max(x-1,0)).
//   row A: y=2r+1 (fy=0, row r);  row B: y=2r+2 (fy=1/2, rows r,r+1)
//   y=0 == y=1 (written when r==0); row B skipped at r==99.
//   x=4q: (L[2q-1]+L[2q])/2   x=4q+1: L[2q]
//   x=4q+2: (L[2q]+L[2q+1])/2 x=4q+3: L[2q+1]   (cols clamped to [0,151])
// ------------------------------------------------------------------------
__global__ __launch_bounds__(256) void dmh_upsample_kernel(
    const __half* __restrict__ logits,  // [3*n_inst][HWSZ]
    float* __restrict__ out)            // [3*n_inst][200][304]
{
    int idx = blockIdx.x * 256 + threadIdx.x;   // 3*n_inst*100*76 threads
    const int q = idx % 76;  idx /= 76;
    const int r = idx % HH;  idx /= HH;         // idx = h*n_inst + n

    const __half* __restrict__ L = logits + (size_t)idx * HWSZ + r * WW;
    float* __restrict__ O = out + (size_t)idx * OUT_PER_INST;

    const int cm = max(2 * q - 1, 0);
    const int c0 = 2 * q;
    const int cp = min(2 * q + 1, WW - 1);
    const int rpOff = (r < HH - 1) ? WW : 0;    // clamp row r+1

    const float Lm0 = __half2float(L[cm]);
    const float L00 = __half2float(L[c0]);
    const float Lp0 = __half2float(L[cp]);
    const float Lm1 = __half2float(L[cm + rpOff]);
    const float L01 = __half2float(L[c0 + rpOff]);
    const float Lp1 = __half2float(L[cp + rpOff]);

    // row A (y = 2r+1)
    const float a0 = 0.5f * (Lm0 + L00);
    const float a1 = L00;
    const float a2 = 0.5f * (L00 + Lp0);
    const float a3 = Lp0;
    // row B (y = 2r+2): average rows first
    const float m  = 0.5f * (Lm0 + Lm1);
    const float z  = 0.5f * (L00 + L01);
    const float pz = 0.5f * (Lp0 + Lp1);
    const float b0 = 0.5f * (m + z);
    const float b1 = z;
    const float b2 = 0.5f * (z + pz);
    const float b3 = pz;

    vf4 A, B;
    A.x = 1.0f / (1.0f + __expf(-a0));
    A.y = 1.0f / (1.0f + __expf(-a1));
    A.z = 1.0f / (1.0f + __expf(-a2));
    A.w = 1.0f / (1.0f + __expf(-a3));
    B.x = 1.0f / (1.0f + __expf(-b0));
    B.y = 1.0f / (1.0f + __expf(-b1));
    B.z = 1.0f / (1.0f + __expf(-b2));
    B.w = 1.0f / (1.0f + __expf(-b3));

    const int xq = 4 * q;
    *(vf4*)(O + (size_t)(2 * r + 1) * OWID + xq) = A;           // y = 2r+1
    if (r == 0)
        *(vf4*)(O + xq) = A;                                     // y = 0 (== y=1)
    if (r < HH - 1)
        *(vf4*)(O + (size_t)(2 * r + 2) * OWID + xq) = B;       // y = 2r+2
}

extern "C" void kernel_launch(void* const* d_in, const int* in_sizes, int n_in,
                              void* d_out, int out_size, void* d_ws, size_t ws_size,
                              hipStream_t stream) {
    const float* fbody   = (const float*)d_in[0];
    const float* fedge   = (const float*)d_in[1];
    const float* params  = (const float*)d_in[2];
    const float* locs    = (const float*)d_in[3];
    const float* soi     = (const float*)d_in[4];
    const int*   im_inds = (const int*)d_in[5];
    const int*   fpn     = (const int*)d_in[6];
    // d_in[7] = mask_feat_stride (always 8; factor=2 baked into the closed form)

    const int n_inst = in_sizes[5];  // 128
    __half* logits = (__half*)d_ws;  // 3*n_inst*HWSZ*2 = 11.7 MB

    dim3 g1((HWSZ / 4 + 255) / 256, n_inst);   // 15 x 128 blocks, 4 px/thread
    dmh_mlp4_kernel<<<g1, dim3(256), 0, stream>>>(
        fbody, fedge, params, locs, soi, im_inds, fpn, logits, n_inst);

    const int total2 = 3 * n_inst * HH * 76;   // (head,inst) x r x q
    dmh_upsample_kernel<<<dim3(total2 / 256), dim3(256), 0, stream>>>(
        logits, (float*)d_out);
}

// Round 10
// 42.607 us; speedup vs baseline: 1.3047x; 1.3047x over previous
//
#include <hip/hip_runtime.h>
#include <hip/hip_bf16.h>
#include <hip/hip_fp16.h>

// Problem constants (fixed by setup_inputs)
#define CIN      8
#define HH       100
#define WW       152
#define HWSZ     (HH * WW)          // 15200
#define OHGT     200
#define OWID     304
#define PPI      419                 // params per instance: 169 body + 169 edge + 81 fused
#define OUT_PER_INST (OHGT * OWID)   // 60800

#define RSTRIP   5                   // interior logit rows per block (100 = 20*5)
#define TROWS    6                   // 5 interior + 1 halo
#define NSTRIPS  20
#define QPT      38                  // quads per row (152/4)
#define P1THREADS (TROWS * QPT)      // 228 active phase-1 threads
#define P2ITEMS  (3 * RSTRIP * 76)   // 1140 upsample items per block

// Per-instance param layout (row of 419 floats):
//  body:  w1[8][10]@0  w2[8][8]@80  w3[8]@144  b1[8]@152 b2[8]@160 b3@168
//  edge:  same +169
//  fused: wf1[8][8]@338 wf2[8]@402 bf1[8]@410 bf2@418

typedef float vf4 __attribute__((ext_vector_type(4)));

// R8-proven formulation: vector w*x+a (compiler fuses + packs v_pk_fma_f32).
// R9 proved the scalarized-fmaf variant is WORSE -- do not "fix" this.
__device__ __forceinline__ vf4 fma4(float w, vf4 x, vf4 a) { return w * x + a; }
__device__ __forceinline__ vf4 relu4(vf4 x) {
    vf4 r; r.x = fmaxf(x.x, 0.f); r.y = fmaxf(x.y, 0.f);
    r.z = fmaxf(x.z, 0.f); r.w = fmaxf(x.w, 0.f); return r;
}

// ------------------------------------------------------------------------
// Fused kernel, 256 threads (R4's fusion failed ONLY at 1024 threads).
// Block = (instance n, 5-row strip s).
// Phase 1: threads 0..227 each compute one 4-px quad of the 6x152 logit
//   tile (5 interior rows + 1 halo) -- exact R8 body -> LDS fp32.
// Phase 2: closed-form x2 aligned_bilinear + sigmoid, NT vf4 stores.
// ------------------------------------------------------------------------
__global__ __launch_bounds__(256) void dmh_fused3_kernel(
    const float* __restrict__ fbody,      // [2][8][H][W]
    const float* __restrict__ fedge,      // [2][8][H][W]
    const float* __restrict__ params,     // [n_inst][419]
    const float* __restrict__ locs,       // [n_inst][2]
    const float* __restrict__ soi_tab,    // [5]
    const int*   __restrict__ im_inds,    // [n_inst]
    const int*   __restrict__ fpn_levels, // [n_inst]
    float* __restrict__ out,              // [3][n_inst][200][304]
    int n_inst)
{
    const int s   = blockIdx.x;
    const int n   = blockIdx.y;
    const int tid = threadIdx.x;
    const int r0  = RSTRIP * s;

    __shared__ float slog[3][TROWS][WW];  // 10.9 KB

    const float* __restrict__ p = params + (size_t)n * PPI;
    const int   im      = im_inds[n];
    const float inv_soi = 1.0f / soi_tab[fpn_levels[n]];
    const float sx = (locs[2 * n]     - 4.0f) * inv_soi;
    const float sy = (locs[2 * n + 1] - 4.0f) * inv_soi;
    const float k8 = 8.0f * inv_soi;

    // ---------------- Phase 1: 4-px-quad dynamic MLPs -> LDS ----------------
    if (tid < P1THREADS) {
        const int rl = tid / QPT;             // 0..5
        const int c  = (tid - rl * QPT) * 4;  // 0,4,...,148
        const int r  = min(r0 + rl, HH - 1);  // halo row clamps (edge-pad)
        const int px = r * WW + c;

        const float dx0 = sx - (float)c * k8;
        const vf4 dx = { dx0, dx0 - k8, dx0 - 2.f * k8, dx0 - 3.f * k8 };
        const float dyv = sy - (float)r * k8;
        const vf4 dy = { dyv, dyv, dyv, dyv };

        const float* __restrict__ fb = fbody + (size_t)im * CIN * HWSZ + px;
        const float* __restrict__ fe = fedge + (size_t)im * CIN * HWSZ + px;

        vf4 in[10], h1[8];

        // body head
        in[0] = dx; in[1] = dy;
        #pragma unroll
        for (int k = 0; k < 8; ++k)
            in[k + 2] = *(const vf4*)(fb + k * HWSZ);   // 16B coalesced
        #pragma unroll
        for (int o = 0; o < 8; ++o) {
            vf4 a = p[152 + o];
            #pragma unroll
            for (int k = 0; k < 10; ++k) a = fma4(p[o * 10 + k], in[k], a);
            h1[o] = relu4(a);
        }
        vf4 h2b[8];
        #pragma unroll
        for (int o = 0; o < 8; ++o) {
            vf4 a = p[160 + o];
            #pragma unroll
            for (int k = 0; k < 8; ++k) a = fma4(p[80 + o * 8 + k], h1[k], a);
            h2b[o] = relu4(a);
        }
        vf4 lb = p[168];
        #pragma unroll
        for (int k = 0; k < 8; ++k) lb = fma4(p[144 + k], h2b[k], lb);

        // edge head (reuses in/h1)
        #pragma unroll
        for (int k = 0; k < 8; ++k)
            in[k + 2] = *(const vf4*)(fe + k * HWSZ);
        #pragma unroll
        for (int o = 0; o < 8; ++o) {
            vf4 a = p[169 + 152 + o];
            #pragma unroll
            for (int k = 0; k < 10; ++k) a = fma4(p[169 + o * 10 + k], in[k], a);
            h1[o] = relu4(a);
        }
        vf4 h2e[8];
        #pragma unroll
        for (int o = 0; o < 8; ++o) {
            vf4 a = p[169 + 160 + o];
            #pragma unroll
            for (int k = 0; k < 8; ++k) a = fma4(p[169 + 80 + o * 8 + k], h1[k], a);
            h2e[o] = relu4(a);
        }
        vf4 le = p[169 + 168];
        #pragma unroll
        for (int k = 0; k < 8; ++k) le = fma4(p[169 + 144 + k], h2e[k], le);

        // fused head on relu(h2b)+relu(h2e)
        vf4 hs[8];
        #pragma unroll
        for (int k = 0; k < 8; ++k) hs[k] = h2b[k] + h2e[k];
        vf4 hf[8];
        #pragma unroll
        for (int o = 0; o < 8; ++o) {
            vf4 a = p[410 + o];
            #pragma unroll
            for (int k = 0; k < 8; ++k) a = fma4(p[338 + o * 8 + k], hs[k], a);
            hf[o] = relu4(a);
        }
        vf4 lf = p[418];
        #pragma unroll
        for (int k = 0; k < 8; ++k) lf = fma4(p[402 + k], hf[k], lf);

        *(vf4*)&slog[0][rl][c] = lb;   // 16B-aligned LDS writes (c%4==0)
        *(vf4*)&slog[1][rl][c] = le;
        *(vf4*)&slog[2][rl][c] = lf;
    }
    __syncthreads();

    // ------- Phase 2: x2 aligned_bilinear + sigmoid + NT vf4 stores -------
    // item = (h, rr, q): output rows y=2r+1 (A), y=2r+2 (B), cols 4q..4q+3.
    //   x=4q: (L[2q-1]+L[2q])/2   x=4q+1: L[2q]
    //   x=4q+2: (L[2q]+L[2q+1])/2 x=4q+3: L[2q+1]  (cols clamped to [0,151])
    // Row B averages LDS rows rr,rr+1 (halo pre-clamped). y=0==y=1 at r==0;
    // row B dropped at r==99.
    for (int it = tid; it < P2ITEMS; it += 256) {
        const int h   = it / (RSTRIP * 76);
        const int rem = it - h * (RSTRIP * 76);
        const int rr  = rem / 76;
        const int q   = rem - rr * 76;
        const int r   = r0 + rr;

        const int cm = max(2 * q - 1, 0);
        const int c0 = 2 * q;
        const int cp = min(2 * q + 1, WW - 1);

        const float Lm0 = slog[h][rr][cm],     L00 = slog[h][rr][c0],     Lp0 = slog[h][rr][cp];
        const float Lm1 = slog[h][rr + 1][cm], L01 = slog[h][rr + 1][c0], Lp1 = slog[h][rr + 1][cp];

        // row A (y = 2r+1)
        const float a0 = 0.5f * (Lm0 + L00);
        const float a1 = L00;
        const float a2 = 0.5f * (L00 + Lp0);
        const float a3 = Lp0;
        // row B (y = 2r+2)
        const float m  = 0.5f * (Lm0 + Lm1);
        const float z  = 0.5f * (L00 + L01);
        const float pz = 0.5f * (Lp0 + Lp1);
        const float b0 = 0.5f * (m + z);
        const float b1 = z;
        const float b2 = 0.5f * (z + pz);
        const float b3 = pz;

        vf4 A, B;
        A.x = 1.0f / (1.0f + __expf(-a0));
        A.y = 1.0f / (1.0f + __expf(-a1));
        A.z = 1.0f / (1.0f + __expf(-a2));
        A.w = 1.0f / (1.0f + __expf(-a3));
        B.x = 1.0f / (1.0f + __expf(-b0));
        B.y = 1.0f / (1.0f + __expf(-b1));
        B.z = 1.0f / (1.0f + __expf(-b2));
        B.w = 1.0f / (1.0f + __expf(-b3));

        float* __restrict__ O = out + ((size_t)h * n_inst + n) * OUT_PER_INST;
        const int xq = 4 * q;
        __builtin_nontemporal_store(A, (vf4*)(O + (size_t)(2 * r + 1) * OWID + xq)); // y=2r+1
        if (r == 0)
            __builtin_nontemporal_store(A, (vf4*)(O + xq));                           // y=0 (==y=1)
        if (r < HH - 1)
            __builtin_nontemporal_store(B, (vf4*)(O + (size_t)(2 * r + 2) * OWID + xq)); // y=2r+2
    }
}

extern "C" void kernel_launch(void* const* d_in, const int* in_sizes, int n_in,
                              void* d_out, int out_size, void* d_ws, size_t ws_size,
                              hipStream_t stream) {
    const float* fbody   = (const float*)d_in[0];
    const float* fedge   = (const float*)d_in[1];
    const float* params  = (const float*)d_in[2];
    const float* locs    = (const float*)d_in[3];
    const float* soi     = (const float*)d_in[4];
    const int*   im_inds = (const int*)d_in[5];
    const int*   fpn     = (const int*)d_in[6];
    // d_in[7] = mask_feat_stride (always 8; factor=2 baked into the closed form)

    const int n_inst = in_sizes[5];  // 128

    dim3 grid(NSTRIPS, n_inst);
    dmh_fused3_kernel<<<grid, dim3(256), 0, stream>>>(
        fbody, fedge, params, locs, soi, im_inds, fpn,
        (float*)d_out, n_inst);
}